// Round 2
// baseline (3497.475 us; speedup 1.0000x reference)
//
#include <hip/hip_runtime.h>
#include <hip/hip_bf16.h>
#include <math.h>

// Problem constants
#define BB 4
#define DMODEL 1024
#define LL 2048
#define DSTATE 16
#define DCONV 4
#define DINNER 2048
#define DTRANK 64
#define BL (BB * LL)          // 8192 rows

// ---------------------------------------------------------------------------
// in_proj GEMM with fused input transpose:
// C (BL x DINNER) = Xview (BL x DMODEL) @ Bw (DINNER x DMODEL)^T
// where Xview[m][k] = x[b][k][l], m = b*LL + l.
// A-tile staged to LDS in [k][m] order with coalesced reads (contiguous in l).
// 64x64 tile, 256 threads, 4x4 micro-tile, K-tile 16.
// ---------------------------------------------------------------------------
__global__ __launch_bounds__(256) void gemm_xin(
    const float* __restrict__ x, const float* __restrict__ Bw,
    float* __restrict__ C)
{
    __shared__ float As[16][68];
    __shared__ float Bs[16][68];
    const int tid = threadIdx.x;
    const int m0 = blockIdx.y * 64;
    const int n0 = blockIdx.x * 64;
    const int b  = m0 >> 11;            // LL = 2048 rows per batch
    const int l0 = m0 & (LL - 1);
    const int mm = tid & 63;            // m within tile (A staging)
    const int kb = tid >> 6;            // 0..3    (A staging)
    const int lrow = tid >> 2;          // 0..63   (B staging)
    const int lk = (tid & 3) * 4;       // 0,4,8,12
    const int tm = tid >> 4;            // 0..15
    const int tn = tid & 15;            // 0..15

    float c[4][4] = {};

    const float* xb = x + (size_t)b * DMODEL * LL + l0 + mm;
    const float* Bptr = Bw + (size_t)(n0 + lrow) * DMODEL + lk;

    for (int k0 = 0; k0 < DMODEL; k0 += 16) {
        float a0 = xb[(size_t)(k0 + kb) * LL];
        float a1 = xb[(size_t)(k0 + kb + 4) * LL];
        float a2 = xb[(size_t)(k0 + kb + 8) * LL];
        float a3 = xb[(size_t)(k0 + kb + 12) * LL];
        float4 bv = *(const float4*)(Bptr + k0);
        __syncthreads();
        As[kb][mm] = a0; As[kb + 4][mm] = a1;
        As[kb + 8][mm] = a2; As[kb + 12][mm] = a3;
        Bs[lk + 0][lrow] = bv.x; Bs[lk + 1][lrow] = bv.y;
        Bs[lk + 2][lrow] = bv.z; Bs[lk + 3][lrow] = bv.w;
        __syncthreads();
#pragma unroll
        for (int kk = 0; kk < 16; ++kk) {
            float4 a = *(const float4*)&As[kk][tm * 4];
            float4 b4 = *(const float4*)&Bs[kk][tn * 4];
            float ar[4] = {a.x, a.y, a.z, a.w};
            float br[4] = {b4.x, b4.y, b4.z, b4.w};
#pragma unroll
            for (int i = 0; i < 4; ++i)
#pragma unroll
                for (int j = 0; j < 4; ++j)
                    c[i][j] = fmaf(ar[i], br[j], c[i][j]);
        }
    }

#pragma unroll
    for (int i = 0; i < 4; ++i)
#pragma unroll
        for (int j = 0; j < 4; ++j)
            C[(size_t)(m0 + tm * 4 + i) * DINNER + n0 + tn * 4 + j] = c[i][j];
}

// ---------------------------------------------------------------------------
// Generic fp32 GEMM: C(M,N) = A(M,K) * Bw(N,K)^T  (+ epilogue)
// epi: 0 = none, 1 = +bias then softplus, 2 = +bias
// M must be a multiple of 64, K a multiple of 16. N guarded.
// ---------------------------------------------------------------------------
__global__ __launch_bounds__(256) void gemm_atb(
    const float* __restrict__ A, const float* __restrict__ Bw,
    float* __restrict__ C, const float* __restrict__ bias,
    int M, int N, int K, int lda, int ldb, int ldc, int epi)
{
    __shared__ float As[16][68];
    __shared__ float Bs[16][68];
    const int tid = threadIdx.x;
    const int m0 = blockIdx.y * 64;
    const int n0 = blockIdx.x * 64;
    const int lrow = tid >> 2;          // 0..63
    const int lk = (tid & 3) * 4;       // 0,4,8,12
    const int tm = tid >> 4;            // 0..15
    const int tn = tid & 15;            // 0..15

    float c[4][4] = {};

    const float* Aptr = A + (size_t)(m0 + lrow) * lda + lk;
    const float* Bptr = Bw + (size_t)(n0 + lrow) * ldb + lk;
    const bool bvalid = (n0 + lrow) < N;

    for (int k0 = 0; k0 < K; k0 += 16) {
        float4 av = *(const float4*)(Aptr + k0);
        float4 bv = make_float4(0.f, 0.f, 0.f, 0.f);
        if (bvalid) bv = *(const float4*)(Bptr + k0);
        __syncthreads();
        As[lk + 0][lrow] = av.x; As[lk + 1][lrow] = av.y;
        As[lk + 2][lrow] = av.z; As[lk + 3][lrow] = av.w;
        Bs[lk + 0][lrow] = bv.x; Bs[lk + 1][lrow] = bv.y;
        Bs[lk + 2][lrow] = bv.z; Bs[lk + 3][lrow] = bv.w;
        __syncthreads();
#pragma unroll
        for (int kk = 0; kk < 16; ++kk) {
            float4 a = *(const float4*)&As[kk][tm * 4];
            float4 b = *(const float4*)&Bs[kk][tn * 4];
            float ar[4] = {a.x, a.y, a.z, a.w};
            float br[4] = {b.x, b.y, b.z, b.w};
#pragma unroll
            for (int i = 0; i < 4; ++i)
#pragma unroll
                for (int j = 0; j < 4; ++j)
                    c[i][j] = fmaf(ar[i], br[j], c[i][j]);
        }
    }

#pragma unroll
    for (int i = 0; i < 4; ++i) {
        int m = m0 + tm * 4 + i;
#pragma unroll
        for (int j = 0; j < 4; ++j) {
            int nn = n0 + tn * 4 + j;
            if (nn < N) {
                float v = c[i][j];
                if (epi >= 1) v += bias[nn];
                if (epi == 1) v = (v > 20.f) ? v : log1pf(__expf(v));
                C[(size_t)m * ldc + nn] = v;
            }
        }
    }
}

// ---------------------------------------------------------------------------
// Depthwise causal conv (width 4) + SiLU. Reads u (BL, DINNER), writes uc.
// ---------------------------------------------------------------------------
__global__ void conv_silu(const float* __restrict__ u, const float* __restrict__ cw,
                          const float* __restrict__ cb, float* __restrict__ uc) {
    int idx = blockIdx.x * 256 + threadIdx.x;     // over BL*DINNER
    int d = idx & (DINNER - 1);
    int bl = idx >> 11;                            // DINNER = 2048 = 2^11
    int l = bl & (LL - 1);
    const float* up = u + (size_t)bl * DINNER + d;
    float4 w = ((const float4*)cw)[d];             // conv_w[d][0..3]
    float acc = cb[d];
    acc = fmaf(w.w, up[0], acc);
    if (l >= 1) acc = fmaf(w.z, up[-DINNER], acc);
    if (l >= 2) acc = fmaf(w.y, up[-2 * DINNER], acc);
    if (l >= 3) acc = fmaf(w.x, up[-3 * DINNER], acc);
    uc[idx] = acc / (1.f + __expf(-acc));          // silu
}

// ---------------------------------------------------------------------------
// Selective scan. One thread per (b, d, n). 16-lane shuffle reduce over n.
// Overwrites uc in place with gated y.
// ---------------------------------------------------------------------------
__global__ __launch_bounds__(256) void scan_kernel(
    const float* __restrict__ delta, const float* __restrict__ xdbl,
    float* __restrict__ uc, const float* __restrict__ z,
    const float* __restrict__ A_log, const float* __restrict__ Dp)
{
    int g = blockIdx.x * 256 + threadIdx.x;        // 0 .. BB*DINNER*16-1
    int n = g & 15;
    int d = (g >> 4) & (DINNER - 1);
    int b = g >> 15;

    float An = -__expf(A_log[d * DSTATE + n]);
    float Dd = Dp[d];
    float h = 0.f;

    const size_t base_bl = (size_t)b * LL;
#pragma unroll 2
    for (int l = 0; l < LL; ++l) {
        size_t bl = base_bl + l;
        float dv = delta[bl * DINNER + d];
        float uv = uc[bl * DINNER + d];
        float Bv = xdbl[bl * 96 + DTRANK + n];
        float Cv = xdbl[bl * 96 + DTRANK + DSTATE + n];
        float dA = __expf(dv * An);
        h = fmaf(dA, h, dv * Bv * uv);
        float y = h * Cv;
        y += __shfl_xor(y, 1);
        y += __shfl_xor(y, 2);
        y += __shfl_xor(y, 4);
        y += __shfl_xor(y, 8);
        if (n == 0) {
            float zv = z[bl * DINNER + d];
            float sz = zv / (1.f + __expf(-zv));
            uc[bl * DINNER + d] = (y + uv * Dd) * sz;
        }
    }
}

// ---------------------------------------------------------------------------
// Tiled transpose: o2 (B*L, DMODEL) -> out (B, DMODEL, L)
// ---------------------------------------------------------------------------
__global__ void transpose_out(const float* __restrict__ o2, float* __restrict__ out) {
    __shared__ float tile[32][33];
    int b = blockIdx.z;
    int l0 = blockIdx.x * 32;
    int e0 = blockIdx.y * 32;
    int tx = threadIdx.x, ty = threadIdx.y;        // 32 x 8
    const float* ob = o2 + (size_t)b * LL * DMODEL;
#pragma unroll
    for (int j = 0; j < 32; j += 8)
        tile[ty + j][tx] = ob[(size_t)(l0 + ty + j) * DMODEL + e0 + tx];
    __syncthreads();
    float* outb = out + (size_t)b * DMODEL * LL;
#pragma unroll
    for (int j = 0; j < 32; j += 8)
        outb[(size_t)(e0 + ty + j) * LL + l0 + tx] = tile[tx][ty + j];
}

// ---------------------------------------------------------------------------
extern "C" void kernel_launch(void* const* d_in, const int* in_sizes, int n_in,
                              void* d_out, int out_size, void* d_ws, size_t ws_size,
                              hipStream_t stream) {
    const float* x         = (const float*)d_in[0];
    const float* in_proj_w = (const float*)d_in[1];
    const float* conv_w    = (const float*)d_in[2];
    const float* conv_b    = (const float*)d_in[3];
    const float* x_proj_w  = (const float*)d_in[4];
    const float* dt_proj_w = (const float*)d_in[5];
    const float* dt_proj_b = (const float*)d_in[6];
    const float* A_log     = (const float*)d_in[7];
    const float* Dp        = (const float*)d_in[8];
    const float* out_proj_w= (const float*)d_in[9];
    const float* proj_w    = (const float*)d_in[10];
    const float* proj_b    = (const float*)d_in[11];
    float* out = (float*)d_out;

    // Workspace layout (floats), total 51,118,080 floats = ~195 MB:
    //   bufU 16M | bufZ 16M | uc 16M | xdbl 768K
    // Reuse: delta = bufU (u dead after conv); out1 = bufU[0:8M] (delta dead
    // after scan); out2 = bufU[8M:16M].
    float* ws   = (float*)d_ws;
    float* bufU = ws;                               // 8192*2048
    float* bufZ = bufU + (size_t)BL * DINNER;       // 8192*2048
    float* uc   = bufZ + (size_t)BL * DINNER;       // 8192*2048
    float* xdbl = uc + (size_t)BL * DINNER;         // 8192*96
    float* delta = bufU;
    float* out1  = bufU;                            // 8192*1024
    float* out2  = bufU + (size_t)BL * DMODEL;      // 8192*1024

    // 1) in_proj (fused transpose read): u and z halves
    gemm_xin<<<dim3(DINNER / 64, BL / 64), 256, 0, stream>>>(x, in_proj_w, bufU);
    gemm_xin<<<dim3(DINNER / 64, BL / 64), 256, 0, stream>>>(
        x, in_proj_w + (size_t)DINNER * DMODEL, bufZ);

    // 2) depthwise conv + silu: uc
    conv_silu<<<dim3(BL * DINNER / 256), 256, 0, stream>>>(bufU, conv_w, conv_b, uc);

    // 3) x_proj: xdbl = uc @ x_proj_w^T   (8192 x 96, K=2048)
    gemm_atb<<<dim3(2, BL / 64), 256, 0, stream>>>(
        uc, x_proj_w, xdbl, nullptr, BL, 96, DINNER, DINNER, DINNER, 96, 0);

    // 4) dt_proj + softplus: delta = softplus(xdbl[:, :64] @ dt_proj_w^T + b)
    gemm_atb<<<dim3(DINNER / 64, BL / 64), 256, 0, stream>>>(
        xdbl, dt_proj_w, delta, dt_proj_b, BL, DINNER, DTRANK, 96, DTRANK, DINNER, 1);

    // 5) selective scan (+ D skip + silu(z) gate), y overwrites uc
    scan_kernel<<<dim3(BB * DINNER * DSTATE / 256), 256, 0, stream>>>(
        delta, xdbl, uc, bufZ, A_log, Dp);

    // 6) out_proj: out1 = y @ out_proj_w^T  (8192 x 1024, K=2048)
    gemm_atb<<<dim3(DMODEL / 64, BL / 64), 256, 0, stream>>>(
        uc, out_proj_w, out1, nullptr, BL, DMODEL, DINNER, DINNER, DINNER, DMODEL, 0);

    // 7) proj: out2 = out1 @ proj_w^T + proj_b  (8192 x 1024, K=1024)
    gemm_atb<<<dim3(DMODEL / 64, BL / 64), 256, 0, stream>>>(
        out1, proj_w, out2, proj_b, BL, DMODEL, DMODEL, DMODEL, DMODEL, DMODEL, 2);

    // 8) out2 -> out (B, DMODEL, L)
    transpose_out<<<dim3(LL / 32, DMODEL / 32, BB), dim3(32, 8), 0, stream>>>(out2, out);
}

// Round 3
// 2605.908 us; speedup vs baseline: 1.3421x; 1.3421x over previous
//
#include <hip/hip_runtime.h>
#include <hip/hip_bf16.h>
#include <math.h>

// Problem constants
#define BB 4
#define DMODEL 1024
#define LL 2048
#define DSTATE 16
#define DCONV 4
#define DINNER 2048
#define DTRANK 64
#define BL (BB * LL)          // 8192 rows
#define NCHUNK 8
#define LCH (LL / NCHUNK)     // 256

// ---------------------------------------------------------------------------
// in_proj GEMM with fused input transpose:
// C (BL x DINNER) = Xview (BL x DMODEL) @ Bw (DINNER x DMODEL)^T
// where Xview[m][k] = x[b][k][l], m = b*LL + l.
// ---------------------------------------------------------------------------
__global__ __launch_bounds__(256) void gemm_xin(
    const float* __restrict__ x, const float* __restrict__ Bw,
    float* __restrict__ C)
{
    __shared__ float As[16][68];
    __shared__ float Bs[16][68];
    const int tid = threadIdx.x;
    const int m0 = blockIdx.y * 64;
    const int n0 = blockIdx.x * 64;
    const int b  = m0 >> 11;            // LL = 2048 rows per batch
    const int l0 = m0 & (LL - 1);
    const int mm = tid & 63;            // m within tile (A staging)
    const int kb = tid >> 6;            // 0..3    (A staging)
    const int lrow = tid >> 2;          // 0..63   (B staging)
    const int lk = (tid & 3) * 4;       // 0,4,8,12
    const int tm = tid >> 4;            // 0..15
    const int tn = tid & 15;            // 0..15

    float c[4][4] = {};

    const float* xb = x + (size_t)b * DMODEL * LL + l0 + mm;
    const float* Bptr = Bw + (size_t)(n0 + lrow) * DMODEL + lk;

    for (int k0 = 0; k0 < DMODEL; k0 += 16) {
        float a0 = xb[(size_t)(k0 + kb) * LL];
        float a1 = xb[(size_t)(k0 + kb + 4) * LL];
        float a2 = xb[(size_t)(k0 + kb + 8) * LL];
        float a3 = xb[(size_t)(k0 + kb + 12) * LL];
        float4 bv = *(const float4*)(Bptr + k0);
        __syncthreads();
        As[kb][mm] = a0; As[kb + 4][mm] = a1;
        As[kb + 8][mm] = a2; As[kb + 12][mm] = a3;
        Bs[lk + 0][lrow] = bv.x; Bs[lk + 1][lrow] = bv.y;
        Bs[lk + 2][lrow] = bv.z; Bs[lk + 3][lrow] = bv.w;
        __syncthreads();
#pragma unroll
        for (int kk = 0; kk < 16; ++kk) {
            float4 a = *(const float4*)&As[kk][tm * 4];
            float4 b4 = *(const float4*)&Bs[kk][tn * 4];
            float ar[4] = {a.x, a.y, a.z, a.w};
            float br[4] = {b4.x, b4.y, b4.z, b4.w};
#pragma unroll
            for (int i = 0; i < 4; ++i)
#pragma unroll
                for (int j = 0; j < 4; ++j)
                    c[i][j] = fmaf(ar[i], br[j], c[i][j]);
        }
    }

#pragma unroll
    for (int i = 0; i < 4; ++i)
#pragma unroll
        for (int j = 0; j < 4; ++j)
            C[(size_t)(m0 + tm * 4 + i) * DINNER + n0 + tn * 4 + j] = c[i][j];
}

// ---------------------------------------------------------------------------
// Generic fp32 GEMM: C(M,N) = A(M,K) * Bw(N,K)^T  (+ epilogue)
// epi: 0 = none, 1 = +bias then softplus, 2 = +bias
// ---------------------------------------------------------------------------
__global__ __launch_bounds__(256) void gemm_atb(
    const float* __restrict__ A, const float* __restrict__ Bw,
    float* __restrict__ C, const float* __restrict__ bias,
    int M, int N, int K, int lda, int ldb, int ldc, int epi)
{
    __shared__ float As[16][68];
    __shared__ float Bs[16][68];
    const int tid = threadIdx.x;
    const int m0 = blockIdx.y * 64;
    const int n0 = blockIdx.x * 64;
    const int lrow = tid >> 2;          // 0..63
    const int lk = (tid & 3) * 4;       // 0,4,8,12
    const int tm = tid >> 4;            // 0..15
    const int tn = tid & 15;            // 0..15

    float c[4][4] = {};

    const float* Aptr = A + (size_t)(m0 + lrow) * lda + lk;
    const float* Bptr = Bw + (size_t)(n0 + lrow) * ldb + lk;
    const bool bvalid = (n0 + lrow) < N;

    for (int k0 = 0; k0 < K; k0 += 16) {
        float4 av = *(const float4*)(Aptr + k0);
        float4 bv = make_float4(0.f, 0.f, 0.f, 0.f);
        if (bvalid) bv = *(const float4*)(Bptr + k0);
        __syncthreads();
        As[lk + 0][lrow] = av.x; As[lk + 1][lrow] = av.y;
        As[lk + 2][lrow] = av.z; As[lk + 3][lrow] = av.w;
        Bs[lk + 0][lrow] = bv.x; Bs[lk + 1][lrow] = bv.y;
        Bs[lk + 2][lrow] = bv.z; Bs[lk + 3][lrow] = bv.w;
        __syncthreads();
#pragma unroll
        for (int kk = 0; kk < 16; ++kk) {
            float4 a = *(const float4*)&As[kk][tm * 4];
            float4 b = *(const float4*)&Bs[kk][tn * 4];
            float ar[4] = {a.x, a.y, a.z, a.w};
            float br[4] = {b.x, b.y, b.z, b.w};
#pragma unroll
            for (int i = 0; i < 4; ++i)
#pragma unroll
                for (int j = 0; j < 4; ++j)
                    c[i][j] = fmaf(ar[i], br[j], c[i][j]);
        }
    }

#pragma unroll
    for (int i = 0; i < 4; ++i) {
        int m = m0 + tm * 4 + i;
#pragma unroll
        for (int j = 0; j < 4; ++j) {
            int nn = n0 + tn * 4 + j;
            if (nn < N) {
                float v = c[i][j];
                if (epi >= 1) v += bias[nn];
                if (epi == 1) v = (v > 20.f) ? v : log1pf(__expf(v));
                C[(size_t)m * ldc + nn] = v;
            }
        }
    }
}

// ---------------------------------------------------------------------------
// Depthwise causal conv (width 4) + SiLU. Reads u (BL, DINNER), writes uc.
// ---------------------------------------------------------------------------
__global__ void conv_silu(const float* __restrict__ u, const float* __restrict__ cw,
                          const float* __restrict__ cb, float* __restrict__ uc) {
    int idx = blockIdx.x * 256 + threadIdx.x;     // over BL*DINNER
    int d = idx & (DINNER - 1);
    int bl = idx >> 11;                            // DINNER = 2048 = 2^11
    int l = bl & (LL - 1);
    const float* up = u + (size_t)bl * DINNER + d;
    float4 w = ((const float4*)cw)[d];             // conv_w[d][0..3]
    float acc = cb[d];
    acc = fmaf(w.w, up[0], acc);
    if (l >= 1) acc = fmaf(w.z, up[-DINNER], acc);
    if (l >= 2) acc = fmaf(w.y, up[-2 * DINNER], acc);
    if (l >= 3) acc = fmaf(w.x, up[-3 * DINNER], acc);
    uc[idx] = acc / (1.f + __expf(-acc));          // silu
}

// ---------------------------------------------------------------------------
// Chunked selective scan, 3 phases. Recurrence per (b,d,n):
//   h[l] = dA[l]*h[l-1] + dv*Bv*uv,  dA = exp(dv*A[d][n])
// Phase 1: per chunk compute P = prod(dA), F = scan result from h=0.
// Index g = ((b*NCHUNK + c)*DINNER + d)*16 + n.
// ---------------------------------------------------------------------------
__global__ __launch_bounds__(256) void scan_phase1(
    const float* __restrict__ delta, const float* __restrict__ xdbl,
    const float* __restrict__ uc, const float* __restrict__ A_log,
    float* __restrict__ P, float* __restrict__ F)
{
    int g = blockIdx.x * 256 + threadIdx.x;
    int n = g & 15;
    int d = (g >> 4) & (DINNER - 1);
    int c = (g >> 15) & (NCHUNK - 1);
    int b = g >> 18;

    float An = -__expf(A_log[d * DSTATE + n]);
    float p = 1.f, f = 0.f;
    size_t bl = (size_t)b * LL + (size_t)c * LCH;
#pragma unroll 2
    for (int l = 0; l < LCH; ++l, ++bl) {
        float dv = delta[bl * DINNER + d];
        float uv = uc[bl * DINNER + d];
        float Bv = xdbl[bl * 96 + DTRANK + n];
        float dA = __expf(dv * An);
        f = fmaf(dA, f, dv * Bv * uv);
        p *= dA;
    }
    P[g] = p; F[g] = f;
}

// Phase 2: serial combine over chunks; Hin[b][c][d][n] = state entering chunk c.
__global__ __launch_bounds__(256) void scan_phase2(
    const float* __restrict__ P, const float* __restrict__ F,
    float* __restrict__ Hin)
{
    int g = blockIdx.x * 256 + threadIdx.x;   // b*(DINNER*16) + d*16 + n
    int dn = g & (DINNER * DSTATE - 1);
    int b = g >> 15;
    float h = 0.f;
#pragma unroll
    for (int c = 0; c < NCHUNK; ++c) {
        size_t idx = ((size_t)(b * NCHUNK + c) << 15) + dn;
        Hin[idx] = h;
        h = fmaf(P[idx], h, F[idx]);
    }
}

// Phase 3: re-run chunk from Hin, produce gated y (overwrites uc in place).
__global__ __launch_bounds__(256) void scan_phase3(
    const float* __restrict__ delta, const float* __restrict__ xdbl,
    float* __restrict__ uc, const float* __restrict__ z,
    const float* __restrict__ A_log, const float* __restrict__ Dp,
    const float* __restrict__ Hin)
{
    int g = blockIdx.x * 256 + threadIdx.x;
    int n = g & 15;
    int d = (g >> 4) & (DINNER - 1);
    int c = (g >> 15) & (NCHUNK - 1);
    int b = g >> 18;

    float An = -__expf(A_log[d * DSTATE + n]);
    float Dd = Dp[d];
    float h = Hin[g];
    size_t bl = (size_t)b * LL + (size_t)c * LCH;
#pragma unroll 2
    for (int l = 0; l < LCH; ++l, ++bl) {
        float dv = delta[bl * DINNER + d];
        float uv = uc[bl * DINNER + d];
        float Bv = xdbl[bl * 96 + DTRANK + n];
        float Cv = xdbl[bl * 96 + DTRANK + DSTATE + n];
        float dA = __expf(dv * An);
        h = fmaf(dA, h, dv * Bv * uv);
        float y = h * Cv;
        y += __shfl_xor(y, 1);
        y += __shfl_xor(y, 2);
        y += __shfl_xor(y, 4);
        y += __shfl_xor(y, 8);
        if (n == 0) {
            float zv = z[bl * DINNER + d];
            float sz = zv / (1.f + __expf(-zv));
            uc[bl * DINNER + d] = (y + uv * Dd) * sz;
        }
    }
}

// ---------------------------------------------------------------------------
// Tiled transpose: o2 (B*L, DMODEL) -> out (B, DMODEL, L)
// ---------------------------------------------------------------------------
__global__ void transpose_out(const float* __restrict__ o2, float* __restrict__ out) {
    __shared__ float tile[32][33];
    int b = blockIdx.z;
    int l0 = blockIdx.x * 32;
    int e0 = blockIdx.y * 32;
    int tx = threadIdx.x, ty = threadIdx.y;        // 32 x 8
    const float* ob = o2 + (size_t)b * LL * DMODEL;
#pragma unroll
    for (int j = 0; j < 32; j += 8)
        tile[ty + j][tx] = ob[(size_t)(l0 + ty + j) * DMODEL + e0 + tx];
    __syncthreads();
    float* outb = out + (size_t)b * DMODEL * LL;
#pragma unroll
    for (int j = 0; j < 32; j += 8)
        outb[(size_t)(e0 + ty + j) * LL + l0 + tx] = tile[tx][ty + j];
}

// ---------------------------------------------------------------------------
extern "C" void kernel_launch(void* const* d_in, const int* in_sizes, int n_in,
                              void* d_out, int out_size, void* d_ws, size_t ws_size,
                              hipStream_t stream) {
    const float* x         = (const float*)d_in[0];
    const float* in_proj_w = (const float*)d_in[1];
    const float* conv_w    = (const float*)d_in[2];
    const float* conv_b    = (const float*)d_in[3];
    const float* x_proj_w  = (const float*)d_in[4];
    const float* dt_proj_w = (const float*)d_in[5];
    const float* dt_proj_b = (const float*)d_in[6];
    const float* A_log     = (const float*)d_in[7];
    const float* Dp        = (const float*)d_in[8];
    const float* out_proj_w= (const float*)d_in[9];
    const float* proj_w    = (const float*)d_in[10];
    const float* proj_b    = (const float*)d_in[11];
    float* out = (float*)d_out;

    // Workspace (floats), total ~207 MB:
    //   bufU 16M | bufZ 16M | uc 16M | xdbl 768K | P 1M | F 1M | Hin 1M
    // Reuse: delta = bufU; out1 = bufU[0:8M]; out2 = bufU[8M:16M].
    float* ws   = (float*)d_ws;
    float* bufU = ws;                               // 8192*2048
    float* bufZ = bufU + (size_t)BL * DINNER;       // 8192*2048
    float* uc   = bufZ + (size_t)BL * DINNER;       // 8192*2048
    float* xdbl = uc + (size_t)BL * DINNER;         // 8192*96
    float* Pbuf = xdbl + (size_t)BL * 96;           // 1M
    float* Fbuf = Pbuf + (size_t)BB * NCHUNK * DINNER * DSTATE;
    float* Hin  = Fbuf + (size_t)BB * NCHUNK * DINNER * DSTATE;
    float* delta = bufU;
    float* out1  = bufU;                            // 8192*1024
    float* out2  = bufU + (size_t)BL * DMODEL;      // 8192*1024

    // 1) in_proj (fused transpose read): u and z halves
    gemm_xin<<<dim3(DINNER / 64, BL / 64), 256, 0, stream>>>(x, in_proj_w, bufU);
    gemm_xin<<<dim3(DINNER / 64, BL / 64), 256, 0, stream>>>(
        x, in_proj_w + (size_t)DINNER * DMODEL, bufZ);

    // 2) depthwise conv + silu: uc
    conv_silu<<<dim3(BL * DINNER / 256), 256, 0, stream>>>(bufU, conv_w, conv_b, uc);

    // 3) x_proj: xdbl = uc @ x_proj_w^T   (8192 x 96, K=2048)
    gemm_atb<<<dim3(2, BL / 64), 256, 0, stream>>>(
        uc, x_proj_w, xdbl, nullptr, BL, 96, DINNER, DINNER, DINNER, 96, 0);

    // 4) dt_proj + softplus: delta = softplus(xdbl[:, :64] @ dt_proj_w^T + b)
    gemm_atb<<<dim3(DINNER / 64, BL / 64), 256, 0, stream>>>(
        xdbl, dt_proj_w, delta, dt_proj_b, BL, DINNER, DTRANK, 96, DTRANK, DINNER, 1);

    // 5) chunked selective scan
    const int scan_threads = BB * NCHUNK * DINNER * DSTATE;      // 1,048,576
    scan_phase1<<<dim3(scan_threads / 256), 256, 0, stream>>>(
        delta, xdbl, uc, A_log, Pbuf, Fbuf);
    scan_phase2<<<dim3(BB * DINNER * DSTATE / 256), 256, 0, stream>>>(
        Pbuf, Fbuf, Hin);
    scan_phase3<<<dim3(scan_threads / 256), 256, 0, stream>>>(
        delta, xdbl, uc, bufZ, A_log, Dp, Hin);

    // 6) out_proj: out1 = y @ out_proj_w^T  (8192 x 1024, K=2048)
    gemm_atb<<<dim3(DMODEL / 64, BL / 64), 256, 0, stream>>>(
        uc, out_proj_w, out1, nullptr, BL, DMODEL, DINNER, DINNER, DINNER, DMODEL, 0);

    // 7) proj: out2 = out1 @ proj_w^T + proj_b  (8192 x 1024, K=1024)
    gemm_atb<<<dim3(DMODEL / 64, BL / 64), 256, 0, stream>>>(
        out1, proj_w, out2, proj_b, BL, DMODEL, DMODEL, DMODEL, DMODEL, DMODEL, 2);

    // 8) out2 -> out (B, DMODEL, L)
    transpose_out<<<dim3(LL / 32, DMODEL / 32, BB), dim3(32, 8), 0, stream>>>(out2, out);
}

// Round 4
// 1160.557 us; speedup vs baseline: 3.0136x; 2.2454x over previous
//
#include <hip/hip_runtime.h>
#include <hip/hip_bf16.h>
#include <math.h>

// Problem constants
#define BB 4
#define DMODEL 1024
#define LL 2048
#define DSTATE 16
#define DCONV 4
#define DINNER 2048
#define DTRANK 64
#define BL (BB * LL)          // 8192 rows
#define NCHUNK 8
#define LCH (LL / NCHUNK)     // 256

typedef unsigned short ushort;
typedef __bf16 bf16x8 __attribute__((ext_vector_type(8)));
typedef float f32x4 __attribute__((ext_vector_type(4)));

__device__ inline ushort f2bf(float f) {
    unsigned int u = __float_as_uint(f);
    u += 0x7fffu + ((u >> 16) & 1u);           // round-to-nearest-even
    return (ushort)(u >> 16);
}
__device__ inline float bf2f(ushort h) {
    return __uint_as_float(((unsigned int)h) << 16);
}

// ---------------------------------------------------------------------------
// fp32 -> bf16 bulk convert (n4 = count/4)
// ---------------------------------------------------------------------------
__global__ void f32_to_bf16(const float* __restrict__ src, ushort* __restrict__ dst, int n4) {
    int i = blockIdx.x * 256 + threadIdx.x;
    if (i < n4) {
        float4 v = ((const float4*)src)[i];
        ushort4 o;
        o.x = f2bf(v.x); o.y = f2bf(v.y); o.z = f2bf(v.z); o.w = f2bf(v.w);
        ((ushort4*)dst)[i] = o;
    }
}

// ---------------------------------------------------------------------------
// x (B, DMODEL, L) fp32 -> xtb (B*L, DMODEL) bf16 (transpose + convert)
// ---------------------------------------------------------------------------
__global__ void transpose_convert_x(const float* __restrict__ x, ushort* __restrict__ xtb) {
    __shared__ float tile[32][33];
    int b = blockIdx.z;
    int l0 = blockIdx.x * 32;
    int d0 = blockIdx.y * 32;
    int tx = threadIdx.x, ty = threadIdx.y;       // 32 x 8
    const float* xb = x + (size_t)b * DMODEL * LL;
#pragma unroll
    for (int j = 0; j < 32; j += 8)
        tile[ty + j][tx] = xb[(size_t)(d0 + ty + j) * LL + l0 + tx];
    __syncthreads();
    ushort* xtbb = xtb + (size_t)b * LL * DMODEL;
#pragma unroll
    for (int j = 0; j < 32; j += 8)
        xtbb[(size_t)(l0 + ty + j) * DMODEL + d0 + tx] = f2bf(tile[tx][ty + j]);
}

// ---------------------------------------------------------------------------
// bf16 MFMA GEMM: C(M,N) = A(M,K) @ Bw(N,K)^T, fp32 accumulate.
// 128x128 block tile, 256 threads (4 waves, 2x2), 4x4 MFMA tiles per wave,
// K-tile 32, LDS rows padded to 40 bf16 (2-way conflicts only = free).
// flags: 1 = write fp32 C (ldc), 2 = write bf16 Cb (ldcb, col<nbmax),
//        4 = add bias[col] (fp32), 8 = softplus.
// Requires: M %128==0, K %32==0, lda/ldb %8==0. N guarded.
// ---------------------------------------------------------------------------
__global__ __launch_bounds__(256) void gemm_bf16(
    const ushort* __restrict__ A, const ushort* __restrict__ Bw,
    float* __restrict__ C, ushort* __restrict__ Cb,
    const float* __restrict__ bias,
    int M, int N, int K, int lda, int ldb, int ldc, int ldcb, int nbmax, int flags)
{
    __shared__ ushort As[128 * 40];
    __shared__ ushort Bs[128 * 40];
    const int tid = threadIdx.x;
    const int m0 = blockIdx.y * 128;
    const int n0 = blockIdx.x * 128;
    const int srow = tid >> 2;                 // 0..63
    const int sseg = (tid & 3) * 8;            // k offset: 0,8,16,24
    const int wave = tid >> 6;
    const int lane = tid & 63;
    const int wm = (wave >> 1) * 64;
    const int wn = (wave & 1) * 64;
    const int fr = lane & 15;
    const int fq = lane >> 4;                  // quad 0..3
    const int fk = fq * 8;

    f32x4 acc[4][4];
#pragma unroll
    for (int i = 0; i < 4; ++i)
#pragma unroll
        for (int j = 0; j < 4; ++j)
            acc[i][j] = (f32x4)(0.0f);

    const ushort* Ap = A + (size_t)(m0 + srow) * lda + sseg;
    const ushort* Bp = Bw + (size_t)(n0 + srow) * ldb + sseg;
    const bool bv0 = (n0 + srow) < N;
    const bool bv1 = (n0 + srow + 64) < N;

    for (int k0 = 0; k0 < K; k0 += 32) {
        uint4 a0 = *(const uint4*)(Ap + k0);
        uint4 a1 = *(const uint4*)(Ap + (size_t)64 * lda + k0);
        uint4 zz = make_uint4(0u, 0u, 0u, 0u);
        uint4 b0 = bv0 ? *(const uint4*)(Bp + k0) : zz;
        uint4 b1 = bv1 ? *(const uint4*)(Bp + (size_t)64 * ldb + k0) : zz;
        __syncthreads();
        *(uint4*)&As[srow * 40 + sseg] = a0;
        *(uint4*)&As[(srow + 64) * 40 + sseg] = a1;
        *(uint4*)&Bs[srow * 40 + sseg] = b0;
        *(uint4*)&Bs[(srow + 64) * 40 + sseg] = b1;
        __syncthreads();
        bf16x8 af[4], bfr[4];
#pragma unroll
        for (int i = 0; i < 4; ++i)
            af[i] = *(const bf16x8*)&As[(wm + i * 16 + fr) * 40 + fk];
#pragma unroll
        for (int j = 0; j < 4; ++j)
            bfr[j] = *(const bf16x8*)&Bs[(wn + j * 16 + fr) * 40 + fk];
#pragma unroll
        for (int i = 0; i < 4; ++i)
#pragma unroll
            for (int j = 0; j < 4; ++j)
                acc[i][j] = __builtin_amdgcn_mfma_f32_16x16x32_bf16(
                    af[i], bfr[j], acc[i][j], 0, 0, 0);
    }

    // Epilogue: C/D layout col=lane&15, row=quad*4+reg (verified m89/m91)
#pragma unroll
    for (int i = 0; i < 4; ++i) {
#pragma unroll
        for (int r = 0; r < 4; ++r) {
            int row = m0 + wm + i * 16 + fq * 4 + r;
#pragma unroll
            for (int j = 0; j < 4; ++j) {
                int col = n0 + wn + j * 16 + fr;
                if (col < N) {
                    float v = acc[i][j][r];
                    if (flags & 4) v += bias[col];
                    if (flags & 8) v = (v > 20.f) ? v : log1pf(__expf(v));
                    if (flags & 1) C[(size_t)row * ldc + col] = v;
                    if ((flags & 2) && col < nbmax)
                        Cb[(size_t)row * ldcb + col] = f2bf(v);
                }
            }
        }
    }
}

// ---------------------------------------------------------------------------
// Depthwise causal conv (width 4) + SiLU. Reads u fp32 (BL, DINNER),
// writes ucb bf16.
// ---------------------------------------------------------------------------
__global__ void conv_silu(const float* __restrict__ u, const float* __restrict__ cw,
                          const float* __restrict__ cb, ushort* __restrict__ ucb) {
    int idx = blockIdx.x * 256 + threadIdx.x;     // over BL*DINNER
    int d = idx & (DINNER - 1);
    int bl = idx >> 11;                            // DINNER = 2048 = 2^11
    int l = bl & (LL - 1);
    const float* up = u + (size_t)bl * DINNER + d;
    float4 w = ((const float4*)cw)[d];             // conv_w[d][0..3]
    float acc = cb[d];
    acc = fmaf(w.w, up[0], acc);
    if (l >= 1) acc = fmaf(w.z, up[-DINNER], acc);
    if (l >= 2) acc = fmaf(w.y, up[-2 * DINNER], acc);
    if (l >= 3) acc = fmaf(w.x, up[-3 * DINNER], acc);
    ucb[idx] = f2bf(acc / (1.f + __expf(-acc)));   // silu
}

// ---------------------------------------------------------------------------
// Chunked selective scan (3 phases). h[l] = exp(dv*A)*h[l-1] + dv*Bv*uv.
// g = ((b*NCHUNK + c)*DINNER + d)*16 + n.
// ---------------------------------------------------------------------------
__global__ __launch_bounds__(256) void scan_phase1(
    const float* __restrict__ delta, const float* __restrict__ xdbl,
    const ushort* __restrict__ ucb, const float* __restrict__ A_log,
    float* __restrict__ P, float* __restrict__ F)
{
    int g = blockIdx.x * 256 + threadIdx.x;
    int n = g & 15;
    int d = (g >> 4) & (DINNER - 1);
    int c = (g >> 15) & (NCHUNK - 1);
    int b = g >> 18;

    float An = -__expf(A_log[d * DSTATE + n]);
    float p = 1.f, f = 0.f;
    size_t bl = (size_t)b * LL + (size_t)c * LCH;
#pragma unroll 2
    for (int l = 0; l < LCH; ++l, ++bl) {
        float dv = delta[bl * DINNER + d];
        float uv = bf2f(ucb[bl * DINNER + d]);
        float Bv = xdbl[bl * 96 + DTRANK + n];
        float dA = __expf(dv * An);
        f = fmaf(dA, f, dv * Bv * uv);
        p *= dA;
    }
    P[g] = p; F[g] = f;
}

__global__ __launch_bounds__(256) void scan_phase2(
    const float* __restrict__ P, const float* __restrict__ F,
    float* __restrict__ Hin)
{
    int g = blockIdx.x * 256 + threadIdx.x;   // b*(DINNER*16) + d*16 + n
    int dn = g & (DINNER * DSTATE - 1);
    int b = g >> 15;
    float h = 0.f;
#pragma unroll
    for (int c = 0; c < NCHUNK; ++c) {
        size_t idx = ((size_t)(b * NCHUNK + c) << 15) + dn;
        Hin[idx] = h;
        h = fmaf(P[idx], h, F[idx]);
    }
}

__global__ __launch_bounds__(256) void scan_phase3(
    const float* __restrict__ delta, const float* __restrict__ xdbl,
    const ushort* __restrict__ ucb, const ushort* __restrict__ zb,
    const float* __restrict__ A_log, const float* __restrict__ Dp,
    const float* __restrict__ Hin, ushort* __restrict__ ybf)
{
    int g = blockIdx.x * 256 + threadIdx.x;
    int n = g & 15;
    int d = (g >> 4) & (DINNER - 1);
    int c = (g >> 15) & (NCHUNK - 1);
    int b = g >> 18;

    float An = -__expf(A_log[d * DSTATE + n]);
    float Dd = Dp[d];
    float h = Hin[g];
    size_t bl = (size_t)b * LL + (size_t)c * LCH;
#pragma unroll 2
    for (int l = 0; l < LCH; ++l, ++bl) {
        float dv = delta[bl * DINNER + d];
        float uv = bf2f(ucb[bl * DINNER + d]);
        float Bv = xdbl[bl * 96 + DTRANK + n];
        float Cv = xdbl[bl * 96 + DTRANK + DSTATE + n];
        float dA = __expf(dv * An);
        h = fmaf(dA, h, dv * Bv * uv);
        float y = h * Cv;
        y += __shfl_xor(y, 1);
        y += __shfl_xor(y, 2);
        y += __shfl_xor(y, 4);
        y += __shfl_xor(y, 8);
        if (n == 0) {
            float zv = bf2f(zb[bl * DINNER + d]);
            float sz = zv / (1.f + __expf(-zv));
            ybf[bl * DINNER + d] = f2bf((y + uv * Dd) * sz);
        }
    }
}

// ---------------------------------------------------------------------------
// Tiled transpose: o2 (B*L, DMODEL) fp32 -> out (B, DMODEL, L)
// ---------------------------------------------------------------------------
__global__ void transpose_out(const float* __restrict__ o2, float* __restrict__ out) {
    __shared__ float tile[32][33];
    int b = blockIdx.z;
    int l0 = blockIdx.x * 32;
    int e0 = blockIdx.y * 32;
    int tx = threadIdx.x, ty = threadIdx.y;        // 32 x 8
    const float* ob = o2 + (size_t)b * LL * DMODEL;
#pragma unroll
    for (int j = 0; j < 32; j += 8)
        tile[ty + j][tx] = ob[(size_t)(l0 + ty + j) * DMODEL + e0 + tx];
    __syncthreads();
    float* outb = out + (size_t)b * DMODEL * LL;
#pragma unroll
    for (int j = 0; j < 32; j += 8)
        outb[(size_t)(e0 + ty + j) * LL + l0 + tx] = tile[tx][ty + j];
}

// ---------------------------------------------------------------------------
extern "C" void kernel_launch(void* const* d_in, const int* in_sizes, int n_in,
                              void* d_out, int out_size, void* d_ws, size_t ws_size,
                              hipStream_t stream) {
    const float* x         = (const float*)d_in[0];
    const float* in_proj_w = (const float*)d_in[1];
    const float* conv_w    = (const float*)d_in[2];
    const float* conv_b    = (const float*)d_in[3];
    const float* x_proj_w  = (const float*)d_in[4];
    const float* dt_proj_w = (const float*)d_in[5];
    const float* dt_proj_b = (const float*)d_in[6];
    const float* A_log     = (const float*)d_in[7];
    const float* Dp        = (const float*)d_in[8];
    const float* out_proj_w= (const float*)d_in[9];
    const float* proj_w    = (const float*)d_in[10];
    const float* proj_b    = (const float*)d_in[11];
    float* out = (float*)d_out;

    // Workspace layout (byte offsets), total ~191 MB:
    //  A [0,64M):    u fp32 -> delta fp32 -> {out1b bf16 @0 (16M), out2 fp32 @16M (32M)}
    //  B [64M,96M):  zb bf16
    //  C [96M,128M): xtb bf16 (16M) -> ucb bf16 (32M)   (xtb dead after in_proj)
    //  D [128M,160M):ybf bf16
    //  E [160M,163M):xdbl fp32 (8192x96)
    //  F [163M,164M):dtlow bf16 (8192x64)
    //  G [164M,176M):P | F | Hin (4M floats each)
    //  H [176M,~191M): bf16 weights: wip 8M | wxp | wdt | wop 4M | wpj 2M
    char* wsb = (char*)d_ws;
    float*  bufU  = (float*)(wsb);
    ushort* zb    = (ushort*)(wsb + ((size_t)64 << 20));
    ushort* xtb   = (ushort*)(wsb + ((size_t)96 << 20));
    ushort* ucb   = (ushort*)(wsb + ((size_t)96 << 20));
    ushort* ybf   = (ushort*)(wsb + ((size_t)128 << 20));
    float*  xdbl  = (float*)(wsb + ((size_t)160 << 20));
    ushort* dtlow = (ushort*)(wsb + ((size_t)163 << 20));
    float*  Pbuf  = (float*)(wsb + ((size_t)164 << 20));
    float*  Fbuf  = (float*)(wsb + ((size_t)168 << 20));
    float*  Hin   = (float*)(wsb + ((size_t)172 << 20));
    ushort* wip   = (ushort*)(wsb + ((size_t)176 << 20));   // 4096x1024
    ushort* wxp   = wip + (size_t)4194304;                   // 96x2048
    ushort* wdt   = wxp + (size_t)196608;                    // 2048x64
    ushort* wop   = wdt + (size_t)131072;                    // 1024x2048
    ushort* wpj   = wop + (size_t)2097152;                   // 1024x1024
    float*  delta = bufU;
    ushort* out1b = (ushort*)(wsb);
    float*  out2  = (float*)(wsb + ((size_t)16 << 20));

    // 0) weight conversions fp32 -> bf16
    f32_to_bf16<<<dim3(4096), 256, 0, stream>>>(in_proj_w, wip, 1048576);
    f32_to_bf16<<<dim3(192),  256, 0, stream>>>(x_proj_w,  wxp, 49152);
    f32_to_bf16<<<dim3(128),  256, 0, stream>>>(dt_proj_w, wdt, 32768);
    f32_to_bf16<<<dim3(2048), 256, 0, stream>>>(out_proj_w, wop, 524288);
    f32_to_bf16<<<dim3(1024), 256, 0, stream>>>(proj_w,    wpj, 262144);

    // 1) x -> xtb (transpose + bf16)
    transpose_convert_x<<<dim3(LL / 32, DMODEL / 32, BB), dim3(32, 8), 0, stream>>>(x, xtb);

    // 2) in_proj: u half -> bufU fp32; z half -> zb bf16
    gemm_bf16<<<dim3(DINNER / 128, BL / 128), 256, 0, stream>>>(
        xtb, wip, bufU, nullptr, nullptr,
        BL, DINNER, DMODEL, DMODEL, DMODEL, DINNER, 0, 0, 1);
    gemm_bf16<<<dim3(DINNER / 128, BL / 128), 256, 0, stream>>>(
        xtb, wip + (size_t)DINNER * DMODEL, nullptr, zb, nullptr,
        BL, DINNER, DMODEL, DMODEL, DMODEL, 0, DINNER, DINNER, 2);

    // 3) depthwise conv + silu: ucb bf16 (overwrites xtb region - xtb dead)
    conv_silu<<<dim3(BL * DINNER / 256), 256, 0, stream>>>(bufU, conv_w, conv_b, ucb);

    // 4) x_proj: xdbl fp32 (full 96) + dtlow bf16 (cols 0..63)
    gemm_bf16<<<dim3(1, BL / 128), 256, 0, stream>>>(
        ucb, wxp, xdbl, dtlow, nullptr,
        BL, 96, DINNER, DINNER, DINNER, 96, DTRANK, DTRANK, 1 | 2);

    // 5) dt_proj + bias + softplus -> delta fp32 (overwrites u - dead)
    gemm_bf16<<<dim3(DINNER / 128, BL / 128), 256, 0, stream>>>(
        dtlow, wdt, delta, nullptr, dt_proj_b,
        BL, DINNER, DTRANK, DTRANK, DTRANK, DINNER, 0, 0, 1 | 4 | 8);

    // 6) chunked selective scan
    const int scan_threads = BB * NCHUNK * DINNER * DSTATE;      // 1,048,576
    scan_phase1<<<dim3(scan_threads / 256), 256, 0, stream>>>(
        delta, xdbl, ucb, A_log, Pbuf, Fbuf);
    scan_phase2<<<dim3(BB * DINNER * DSTATE / 256), 256, 0, stream>>>(
        Pbuf, Fbuf, Hin);
    scan_phase3<<<dim3(scan_threads / 256), 256, 0, stream>>>(
        delta, xdbl, ucb, zb, A_log, Dp, Hin, ybf);

    // 7) out_proj: out1b bf16 = y @ out_proj_w^T
    gemm_bf16<<<dim3(DMODEL / 128, BL / 128), 256, 0, stream>>>(
        ybf, wop, nullptr, out1b, nullptr,
        BL, DMODEL, DINNER, DINNER, DINNER, 0, DMODEL, DMODEL, 2);

    // 8) proj: out2 fp32 = out1b @ proj_w^T + proj_b
    gemm_bf16<<<dim3(DMODEL / 128, BL / 128), 256, 0, stream>>>(
        out1b, wpj, out2, nullptr, proj_b,
        BL, DMODEL, DMODEL, DMODEL, DMODEL, DMODEL, 0, 0, 1 | 4);

    // 9) out2 -> out (B, DMODEL, L)
    transpose_out<<<dim3(LL / 32, DMODEL / 32, BB), dim3(32, 8), 0, stream>>>(out2, out);
}

// Round 5
// 804.546 us; speedup vs baseline: 4.3471x; 1.4425x over previous
//
#include <hip/hip_runtime.h>
#include <hip/hip_bf16.h>
#include <math.h>

// Problem constants
#define BB 4
#define DMODEL 1024
#define LL 2048
#define DSTATE 16
#define DCONV 4
#define DINNER 2048
#define DTRANK 64
#define BL (BB * LL)          // 8192 rows
#define NCHUNK 16
#define LCH (LL / NCHUNK)     // 128
#define PFPLANE (BB * DINNER * DSTATE)   // 131072 floats per chunk-plane

typedef unsigned short ushort;
typedef __bf16 bf16x8 __attribute__((ext_vector_type(8)));
typedef float f32x4 __attribute__((ext_vector_type(4)));

__device__ inline ushort f2bf(float f) {
    unsigned int u = __float_as_uint(f);
    u += 0x7fffu + ((u >> 16) & 1u);           // round-to-nearest-even
    return (ushort)(u >> 16);
}
__device__ inline float bf2f(ushort h) {
    return __uint_as_float(((unsigned int)h) << 16);
}

// ---------------------------------------------------------------------------
// fp32 -> bf16 bulk convert (n4 = count/4)
// ---------------------------------------------------------------------------
__global__ void f32_to_bf16(const float* __restrict__ src, ushort* __restrict__ dst, int n4) {
    int i = blockIdx.x * 256 + threadIdx.x;
    if (i < n4) {
        float4 v = ((const float4*)src)[i];
        ushort4 o;
        o.x = f2bf(v.x); o.y = f2bf(v.y); o.z = f2bf(v.z); o.w = f2bf(v.w);
        ((ushort4*)dst)[i] = o;
    }
}

// ---------------------------------------------------------------------------
// x (B, DMODEL, L) fp32 -> xtb (B*L, DMODEL) bf16 (transpose + convert)
// ---------------------------------------------------------------------------
__global__ void transpose_convert_x(const float* __restrict__ x, ushort* __restrict__ xtb) {
    __shared__ float tile[32][33];
    int b = blockIdx.z;
    int l0 = blockIdx.x * 32;
    int d0 = blockIdx.y * 32;
    int tx = threadIdx.x, ty = threadIdx.y;       // 32 x 8
    const float* xb = x + (size_t)b * DMODEL * LL;
#pragma unroll
    for (int j = 0; j < 32; j += 8)
        tile[ty + j][tx] = xb[(size_t)(d0 + ty + j) * LL + l0 + tx];
    __syncthreads();
    ushort* xtbb = xtb + (size_t)b * LL * DMODEL;
#pragma unroll
    for (int j = 0; j < 32; j += 8)
        xtbb[(size_t)(l0 + ty + j) * DMODEL + d0 + tx] = f2bf(tile[tx][ty + j]);
}

// ---------------------------------------------------------------------------
// bf16 MFMA GEMM: C(M,N) = A(M,K) @ Bw(N,K)^T, fp32 accumulate.
// 128x128 block tile, 256 threads (4 waves, 2x2), 4x4 MFMA tiles per wave,
// K-tile 32, LDS rows padded to 40 bf16 (2-way conflicts only = free).
// flags: 1 = write fp32 C (ldc), 2 = write bf16 Cb (ldcb, col<nbmax),
//        4 = add bias[col] (fp32), 8 = softplus.
// ---------------------------------------------------------------------------
__global__ __launch_bounds__(256) void gemm_bf16(
    const ushort* __restrict__ A, const ushort* __restrict__ Bw,
    float* __restrict__ C, ushort* __restrict__ Cb,
    const float* __restrict__ bias,
    int M, int N, int K, int lda, int ldb, int ldc, int ldcb, int nbmax, int flags)
{
    __shared__ ushort As[128 * 40];
    __shared__ ushort Bs[128 * 40];
    const int tid = threadIdx.x;
    const int m0 = blockIdx.y * 128;
    const int n0 = blockIdx.x * 128;
    const int srow = tid >> 2;                 // 0..63
    const int sseg = (tid & 3) * 8;            // k offset: 0,8,16,24
    const int wave = tid >> 6;
    const int lane = tid & 63;
    const int wm = (wave >> 1) * 64;
    const int wn = (wave & 1) * 64;
    const int fr = lane & 15;
    const int fq = lane >> 4;                  // quad 0..3
    const int fk = fq * 8;

    f32x4 acc[4][4];
#pragma unroll
    for (int i = 0; i < 4; ++i)
#pragma unroll
        for (int j = 0; j < 4; ++j)
            acc[i][j] = (f32x4)(0.0f);

    const ushort* Ap = A + (size_t)(m0 + srow) * lda + sseg;
    const ushort* Bp = Bw + (size_t)(n0 + srow) * ldb + sseg;
    const bool bv0 = (n0 + srow) < N;
    const bool bv1 = (n0 + srow + 64) < N;

    for (int k0 = 0; k0 < K; k0 += 32) {
        uint4 a0 = *(const uint4*)(Ap + k0);
        uint4 a1 = *(const uint4*)(Ap + (size_t)64 * lda + k0);
        uint4 zz = make_uint4(0u, 0u, 0u, 0u);
        uint4 b0 = bv0 ? *(const uint4*)(Bp + k0) : zz;
        uint4 b1 = bv1 ? *(const uint4*)(Bp + (size_t)64 * ldb + k0) : zz;
        __syncthreads();
        *(uint4*)&As[srow * 40 + sseg] = a0;
        *(uint4*)&As[(srow + 64) * 40 + sseg] = a1;
        *(uint4*)&Bs[srow * 40 + sseg] = b0;
        *(uint4*)&Bs[(srow + 64) * 40 + sseg] = b1;
        __syncthreads();
        bf16x8 af[4], bfr[4];
#pragma unroll
        for (int i = 0; i < 4; ++i)
            af[i] = *(const bf16x8*)&As[(wm + i * 16 + fr) * 40 + fk];
#pragma unroll
        for (int j = 0; j < 4; ++j)
            bfr[j] = *(const bf16x8*)&Bs[(wn + j * 16 + fr) * 40 + fk];
#pragma unroll
        for (int i = 0; i < 4; ++i)
#pragma unroll
            for (int j = 0; j < 4; ++j)
                acc[i][j] = __builtin_amdgcn_mfma_f32_16x16x32_bf16(
                    af[i], bfr[j], acc[i][j], 0, 0, 0);
    }

    // Epilogue: C/D layout col=lane&15, row=quad*4+reg (verified m89/m91)
#pragma unroll
    for (int i = 0; i < 4; ++i) {
#pragma unroll
        for (int r = 0; r < 4; ++r) {
            int row = m0 + wm + i * 16 + fq * 4 + r;
#pragma unroll
            for (int j = 0; j < 4; ++j) {
                int col = n0 + wn + j * 16 + fr;
                if (col < N) {
                    float v = acc[i][j][r];
                    if (flags & 4) v += bias[col];
                    if (flags & 8) v = (v > 20.f) ? v : log1pf(__expf(v));
                    if (flags & 1) C[(size_t)row * ldc + col] = v;
                    if ((flags & 2) && col < nbmax)
                        Cb[(size_t)row * ldcb + col] = f2bf(v);
                }
            }
        }
    }
}

// ---------------------------------------------------------------------------
// Depthwise causal conv (width 4) + SiLU. Reads u fp32 (BL, DINNER),
// writes ucb bf16.
// ---------------------------------------------------------------------------
__global__ void conv_silu(const float* __restrict__ u, const float* __restrict__ cw,
                          const float* __restrict__ cb, ushort* __restrict__ ucb) {
    int idx = blockIdx.x * 256 + threadIdx.x;     // over BL*DINNER
    int d = idx & (DINNER - 1);
    int bl = idx >> 11;                            // DINNER = 2048 = 2^11
    int l = bl & (LL - 1);
    const float* up = u + (size_t)bl * DINNER + d;
    float4 w = ((const float4*)cw)[d];             // conv_w[d][0..3]
    float acc = cb[d];
    acc = fmaf(w.w, up[0], acc);
    if (l >= 1) acc = fmaf(w.z, up[-DINNER], acc);
    if (l >= 2) acc = fmaf(w.y, up[-2 * DINNER], acc);
    if (l >= 3) acc = fmaf(w.x, up[-3 * DINNER], acc);
    ucb[idx] = f2bf(acc / (1.f + __expf(-acc)));   // silu
}

// ---------------------------------------------------------------------------
// Chunked selective scan, restructured: one thread per (b, chunk, d) with all
// 16 n-states in registers. Coalesced delta/uc/z/y streams (lane = d);
// B/C rows are block-uniform float4 broadcasts.
// Thread index: g = (b*NCHUNK + c)*DINNER + d.
// P/F/Hin layout: [c][ (b*DINNER+d)*16 + n ]  (plane stride PFPLANE).
// ---------------------------------------------------------------------------
__global__ __launch_bounds__(256) void scan_phase1(
    const float* __restrict__ delta, const float* __restrict__ xdbl,
    const ushort* __restrict__ ucb, const float* __restrict__ A_log,
    float* __restrict__ P, float* __restrict__ F)
{
    int g = blockIdx.x * 256 + threadIdx.x;
    int d = g & (DINNER - 1);
    int c = (g >> 11) & (NCHUNK - 1);
    int b = g >> 15;

    float An[16], p[16], f[16];
    const float4* alp = (const float4*)(A_log + (size_t)d * DSTATE);
#pragma unroll
    for (int q = 0; q < 4; ++q) {
        float4 a = alp[q];
        An[q * 4 + 0] = -__expf(a.x); An[q * 4 + 1] = -__expf(a.y);
        An[q * 4 + 2] = -__expf(a.z); An[q * 4 + 3] = -__expf(a.w);
    }
#pragma unroll
    for (int n = 0; n < 16; ++n) { p[n] = 1.f; f[n] = 0.f; }

    size_t bl0 = (size_t)b * LL + (size_t)c * LCH;
    const float* dptr = delta + bl0 * DINNER + d;
    const ushort* uptr = ucb + bl0 * DINNER + d;
    const float* xptr = xdbl + bl0 * 96 + DTRANK;

    for (int l = 0; l < LCH; ++l) {
        float dv = dptr[(size_t)l * DINNER];
        float du = dv * bf2f(uptr[(size_t)l * DINNER]);
        float4 B0 = *(const float4*)(xptr + (size_t)l * 96);
        float4 B1 = *(const float4*)(xptr + (size_t)l * 96 + 4);
        float4 B2 = *(const float4*)(xptr + (size_t)l * 96 + 8);
        float4 B3 = *(const float4*)(xptr + (size_t)l * 96 + 12);
        float Bv[16] = {B0.x, B0.y, B0.z, B0.w, B1.x, B1.y, B1.z, B1.w,
                        B2.x, B2.y, B2.z, B2.w, B3.x, B3.y, B3.z, B3.w};
#pragma unroll
        for (int n = 0; n < 16; ++n) {
            float dA = __expf(dv * An[n]);
            f[n] = fmaf(dA, f[n], du * Bv[n]);
            p[n] *= dA;
        }
    }
    size_t o = (size_t)c * PFPLANE + ((size_t)(b * DINNER + d) << 4);
#pragma unroll
    for (int q = 0; q < 4; ++q) {
        *(float4*)(P + o + q * 4) = make_float4(p[q*4], p[q*4+1], p[q*4+2], p[q*4+3]);
        *(float4*)(F + o + q * 4) = make_float4(f[q*4], f[q*4+1], f[q*4+2], f[q*4+3]);
    }
}

// Phase 2: serial combine over chunks (coalesced per chunk-plane).
__global__ __launch_bounds__(256) void scan_phase2(
    const float* __restrict__ P, const float* __restrict__ F,
    float* __restrict__ Hin)
{
    int g = blockIdx.x * 256 + threadIdx.x;   // (b*DINNER+d)*16 + n
    float h = 0.f;
#pragma unroll
    for (int c = 0; c < NCHUNK; ++c) {
        size_t idx = (size_t)c * PFPLANE + g;
        Hin[idx] = h;
        h = fmaf(P[idx], h, F[idx]);
    }
}

__global__ __launch_bounds__(256) void scan_phase3(
    const float* __restrict__ delta, const float* __restrict__ xdbl,
    const ushort* __restrict__ ucb, const ushort* __restrict__ zb,
    const float* __restrict__ A_log, const float* __restrict__ Dp,
    const float* __restrict__ Hin, ushort* __restrict__ ybf)
{
    int g = blockIdx.x * 256 + threadIdx.x;
    int d = g & (DINNER - 1);
    int c = (g >> 11) & (NCHUNK - 1);
    int b = g >> 15;

    float An[16], h[16];
    const float4* alp = (const float4*)(A_log + (size_t)d * DSTATE);
#pragma unroll
    for (int q = 0; q < 4; ++q) {
        float4 a = alp[q];
        An[q * 4 + 0] = -__expf(a.x); An[q * 4 + 1] = -__expf(a.y);
        An[q * 4 + 2] = -__expf(a.z); An[q * 4 + 3] = -__expf(a.w);
    }
    size_t o = (size_t)c * PFPLANE + ((size_t)(b * DINNER + d) << 4);
#pragma unroll
    for (int q = 0; q < 4; ++q) {
        float4 hv = *(const float4*)(Hin + o + q * 4);
        h[q * 4 + 0] = hv.x; h[q * 4 + 1] = hv.y;
        h[q * 4 + 2] = hv.z; h[q * 4 + 3] = hv.w;
    }
    float Dd = Dp[d];

    size_t bl0 = (size_t)b * LL + (size_t)c * LCH;
    const float* dptr = delta + bl0 * DINNER + d;
    const ushort* uptr = ucb + bl0 * DINNER + d;
    const ushort* zptr = zb + bl0 * DINNER + d;
    const float* xptr = xdbl + bl0 * 96 + DTRANK;
    ushort* yptr = ybf + bl0 * DINNER + d;

    for (int l = 0; l < LCH; ++l) {
        float dv = dptr[(size_t)l * DINNER];
        float uv = bf2f(uptr[(size_t)l * DINNER]);
        float zv = bf2f(zptr[(size_t)l * DINNER]);
        float du = dv * uv;
        float4 B0 = *(const float4*)(xptr + (size_t)l * 96);
        float4 B1 = *(const float4*)(xptr + (size_t)l * 96 + 4);
        float4 B2 = *(const float4*)(xptr + (size_t)l * 96 + 8);
        float4 B3 = *(const float4*)(xptr + (size_t)l * 96 + 12);
        float4 C0 = *(const float4*)(xptr + (size_t)l * 96 + 16);
        float4 C1 = *(const float4*)(xptr + (size_t)l * 96 + 20);
        float4 C2 = *(const float4*)(xptr + (size_t)l * 96 + 24);
        float4 C3 = *(const float4*)(xptr + (size_t)l * 96 + 28);
        float Bv[16] = {B0.x, B0.y, B0.z, B0.w, B1.x, B1.y, B1.z, B1.w,
                        B2.x, B2.y, B2.z, B2.w, B3.x, B3.y, B3.z, B3.w};
        float Cv[16] = {C0.x, C0.y, C0.z, C0.w, C1.x, C1.y, C1.z, C1.w,
                        C2.x, C2.y, C2.z, C2.w, C3.x, C3.y, C3.z, C3.w};
        float y = 0.f;
#pragma unroll
        for (int n = 0; n < 16; ++n) {
            float dA = __expf(dv * An[n]);
            h[n] = fmaf(dA, h[n], du * Bv[n]);
            y = fmaf(h[n], Cv[n], y);
        }
        float sz = zv / (1.f + __expf(-zv));
        yptr[(size_t)l * DINNER] = f2bf((y + uv * Dd) * sz);
    }
}

// ---------------------------------------------------------------------------
// Tiled transpose: o2 (B*L, DMODEL) fp32 -> out (B, DMODEL, L)
// ---------------------------------------------------------------------------
__global__ void transpose_out(const float* __restrict__ o2, float* __restrict__ out) {
    __shared__ float tile[32][33];
    int b = blockIdx.z;
    int l0 = blockIdx.x * 32;
    int e0 = blockIdx.y * 32;
    int tx = threadIdx.x, ty = threadIdx.y;        // 32 x 8
    const float* ob = o2 + (size_t)b * LL * DMODEL;
#pragma unroll
    for (int j = 0; j < 32; j += 8)
        tile[ty + j][tx] = ob[(size_t)(l0 + ty + j) * DMODEL + e0 + tx];
    __syncthreads();
    float* outb = out + (size_t)b * DMODEL * LL;
#pragma unroll
    for (int j = 0; j < 32; j += 8)
        outb[(size_t)(e0 + ty + j) * LL + l0 + tx] = tile[tx][ty + j];
}

// ---------------------------------------------------------------------------
extern "C" void kernel_launch(void* const* d_in, const int* in_sizes, int n_in,
                              void* d_out, int out_size, void* d_ws, size_t ws_size,
                              hipStream_t stream) {
    const float* x         = (const float*)d_in[0];
    const float* in_proj_w = (const float*)d_in[1];
    const float* conv_w    = (const float*)d_in[2];
    const float* conv_b    = (const float*)d_in[3];
    const float* x_proj_w  = (const float*)d_in[4];
    const float* dt_proj_w = (const float*)d_in[5];
    const float* dt_proj_b = (const float*)d_in[6];
    const float* A_log     = (const float*)d_in[7];
    const float* Dp        = (const float*)d_in[8];
    const float* out_proj_w= (const float*)d_in[9];
    const float* proj_w    = (const float*)d_in[10];
    const float* proj_b    = (const float*)d_in[11];
    float* out = (float*)d_out;

    // Workspace layout (byte offsets), total ~203 MB:
    //  A [0,64M):    u fp32 -> delta fp32 -> {out1b bf16 @0, out2 fp32 @16M}
    //  B [64M,96M):  zb bf16
    //  C [96M,128M): xtb bf16 -> ucb bf16
    //  D [128M,160M):ybf bf16
    //  E [160M,163M):xdbl fp32 (8192x96)
    //  F [163M,164M):dtlow bf16 (8192x64)
    //  W [164M,~179M): bf16 weights: wip 8M | wxp | wdt | wop 4M | wpj 2M
    //  G [179M,203M): P | F | Hin (8 MB each, NCHUNK=16 chunk-major)
    char* wsb = (char*)d_ws;
    float*  bufU  = (float*)(wsb);
    ushort* zb    = (ushort*)(wsb + ((size_t)64 << 20));
    ushort* xtb   = (ushort*)(wsb + ((size_t)96 << 20));
    ushort* ucb   = (ushort*)(wsb + ((size_t)96 << 20));
    ushort* ybf   = (ushort*)(wsb + ((size_t)128 << 20));
    float*  xdbl  = (float*)(wsb + ((size_t)160 << 20));
    ushort* dtlow = (ushort*)(wsb + ((size_t)163 << 20));
    ushort* wip   = (ushort*)(wsb + ((size_t)164 << 20));   // 4096x1024
    ushort* wxp   = wip + (size_t)4194304;                   // 96x2048
    ushort* wdt   = wxp + (size_t)196608;                    // 2048x64
    ushort* wop   = wdt + (size_t)131072;                    // 1024x2048
    ushort* wpj   = wop + (size_t)2097152;                   // 1024x1024
    float*  Pbuf  = (float*)(wsb + ((size_t)179 << 20));
    float*  Fbuf  = (float*)(wsb + ((size_t)187 << 20));
    float*  Hin   = (float*)(wsb + ((size_t)195 << 20));
    float*  delta = bufU;
    ushort* out1b = (ushort*)(wsb);
    float*  out2  = (float*)(wsb + ((size_t)16 << 20));

    // 0) weight conversions fp32 -> bf16
    f32_to_bf16<<<dim3(4096), 256, 0, stream>>>(in_proj_w, wip, 1048576);
    f32_to_bf16<<<dim3(192),  256, 0, stream>>>(x_proj_w,  wxp, 49152);
    f32_to_bf16<<<dim3(128),  256, 0, stream>>>(dt_proj_w, wdt, 32768);
    f32_to_bf16<<<dim3(2048), 256, 0, stream>>>(out_proj_w, wop, 524288);
    f32_to_bf16<<<dim3(1024), 256, 0, stream>>>(proj_w,    wpj, 262144);

    // 1) x -> xtb (transpose + bf16)
    transpose_convert_x<<<dim3(LL / 32, DMODEL / 32, BB), dim3(32, 8), 0, stream>>>(x, xtb);

    // 2) in_proj: u half -> bufU fp32; z half -> zb bf16
    gemm_bf16<<<dim3(DINNER / 128, BL / 128), 256, 0, stream>>>(
        xtb, wip, bufU, nullptr, nullptr,
        BL, DINNER, DMODEL, DMODEL, DMODEL, DINNER, 0, 0, 1);
    gemm_bf16<<<dim3(DINNER / 128, BL / 128), 256, 0, stream>>>(
        xtb, wip + (size_t)DINNER * DMODEL, nullptr, zb, nullptr,
        BL, DINNER, DMODEL, DMODEL, DMODEL, 0, DINNER, DINNER, 2);

    // 3) depthwise conv + silu: ucb bf16 (overwrites xtb region - xtb dead)
    conv_silu<<<dim3(BL * DINNER / 256), 256, 0, stream>>>(bufU, conv_w, conv_b, ucb);

    // 4) x_proj: xdbl fp32 (full 96) + dtlow bf16 (cols 0..63)
    gemm_bf16<<<dim3(1, BL / 128), 256, 0, stream>>>(
        ucb, wxp, xdbl, dtlow, nullptr,
        BL, 96, DINNER, DINNER, DINNER, 96, DTRANK, DTRANK, 1 | 2);

    // 5) dt_proj + bias + softplus -> delta fp32 (overwrites u - dead)
    gemm_bf16<<<dim3(DINNER / 128, BL / 128), 256, 0, stream>>>(
        dtlow, wdt, delta, nullptr, dt_proj_b,
        BL, DINNER, DTRANK, DTRANK, DTRANK, DINNER, 0, 0, 1 | 4 | 8);

    // 6) chunked selective scan (one thread per (b,c,d), 16 n-states in regs)
    const int scan_threads = BB * NCHUNK * DINNER;               // 131072
    scan_phase1<<<dim3(scan_threads / 256), 256, 0, stream>>>(
        delta, xdbl, ucb, A_log, Pbuf, Fbuf);
    scan_phase2<<<dim3(PFPLANE / 256), 256, 0, stream>>>(
        Pbuf, Fbuf, Hin);
    scan_phase3<<<dim3(scan_threads / 256), 256, 0, stream>>>(
        delta, xdbl, ucb, zb, A_log, Dp, Hin, ybf);

    // 7) out_proj: out1b bf16 = y @ out_proj_w^T
    gemm_bf16<<<dim3(DMODEL / 128, BL / 128), 256, 0, stream>>>(
        ybf, wop, nullptr, out1b, nullptr,
        BL, DMODEL, DINNER, DINNER, DINNER, 0, DMODEL, DMODEL, 2);

    // 8) proj: out2 fp32 = out1b @ proj_w^T + proj_b
    gemm_bf16<<<dim3(DMODEL / 128, BL / 128), 256, 0, stream>>>(
        out1b, wpj, out2, nullptr, proj_b,
        BL, DMODEL, DMODEL, DMODEL, DMODEL, DMODEL, 0, 0, 1 | 4);

    // 9) out2 -> out (B, DMODEL, L)
    transpose_out<<<dim3(LL / 32, DMODEL / 32, BB), dim3(32, 8), 0, stream>>>(out2, out);
}